// Round 7
// baseline (408.207 us; speedup 1.0000x reference)
//
#include <hip/hip_runtime.h>
#include <math.h>

typedef __attribute__((ext_vector_type(4))) float f32x4;
typedef __attribute__((ext_vector_type(16))) float f32x16;
typedef __attribute__((ext_vector_type(8))) short s16x8;
typedef __attribute__((ext_vector_type(4))) short s16x4;

#define DD 512
#define TT 1024
#define NB 48

__device__ __forceinline__ short f2bf(float f) {
    union { float f; unsigned u; } v; v.f = f;
    unsigned r = v.u + 0x7fffu + ((v.u >> 16) & 1u);
    return (short)(r >> 16);
}

__device__ __forceinline__ void gll16(const void* g, void* l) {
    __builtin_amdgcn_global_load_lds(
        (const __attribute__((address_space(1))) unsigned int*)g,
        (__attribute__((address_space(3))) unsigned int*)l, 16, 0, 0);
}

__device__ __forceinline__ unsigned pk_bf16(float lo, float hi) {
    unsigned r;
    asm("v_cvt_pk_bf16_f32 %0, %1, %2" : "=v"(r) : "v"(lo), "v"(hi));
    return r;
}

// ---------------- LayerNorm stats: one wave per row ----------------
__global__ __launch_bounds__(256) void k_ln_stats(const float* __restrict__ x,
                                                  float* __restrict__ stats) {
    int row = blockIdx.x * 4 + (threadIdx.x >> 6);
    int lane = threadIdx.x & 63;
    const float* p = x + (size_t)row * DD + lane * 8;
    f32x4 a = *(const f32x4*)p;
    f32x4 b = *(const f32x4*)(p + 4);
    float s  = a[0]+a[1]+a[2]+a[3]+b[0]+b[1]+b[2]+b[3];
    float ss = a[0]*a[0]+a[1]*a[1]+a[2]*a[2]+a[3]*a[3]
             + b[0]*b[0]+b[1]*b[1]+b[2]*b[2]+b[3]*b[3];
    #pragma unroll
    for (int off = 32; off >= 1; off >>= 1) {
        s  += __shfl_xor(s, off);
        ss += __shfl_xor(ss, off);
    }
    if (lane == 0) {
        float mu  = s * (1.0f/DD);
        float var = ss * (1.0f/DD) - mu*mu;
        float2 st; st.x = mu; st.y = rsqrtf(var + 1e-5f);
        *(float2*)(stats + (size_t)row*2) = st;
    }
}

// ---------------- gate -> gateT (bf16) ----------------
__global__ __launch_bounds__(256) void k_gate_t(const float* __restrict__ gate,
                                                short* __restrict__ gateT) {
    __shared__ float tile[64][65];
    int k0 = (blockIdx.x >> 3) * 64;
    int n0 = (blockIdx.x & 7) * 64;
    int tid = threadIdx.x;
    #pragma unroll
    for (int i = 0; i < 16; ++i) {
        int f = i*256 + tid;
        int r = f >> 6, c = f & 63;
        tile[r][c] = gate[(size_t)(k0+r)*DD + n0 + c];
    }
    __syncthreads();
    #pragma unroll
    for (int i = 0; i < 16; ++i) {
        int f = i*256 + tid;
        int r = f >> 6, c = f & 63;
        gateT[(size_t)(n0+r)*DD + k0 + c] = f2bf(tile[c][r]);
    }
}

// ------- qkv = LN(x) @ gate  (bf16 MFMA, 128x128 tile, BK=64), also writes qkvT -------
__global__ __launch_bounds__(256,2) void k_qkv(const float* __restrict__ x,
                                               const float* __restrict__ stats,
                                               const short* __restrict__ gateT,
                                               short* __restrict__ qkv,
                                               short* __restrict__ qkvT) {
    __shared__ __align__(16) short As[128][72];
    __shared__ __align__(16) short Bs[128][72];
    int m0 = (blockIdx.x >> 2) * 128;
    int n0 = (blockIdx.x & 3) * 128;
    int tid = threadIdx.x, lane = tid & 63, w = tid >> 6;
    int wr = w >> 1, wc = w & 1;
    int l15 = lane & 15, lg = lane >> 4;
    f32x4 acc[4][4];
    #pragma unroll
    for (int i=0;i<4;i++)
      #pragma unroll
      for (int j=0;j<4;j++)
        acc[i][j] = (f32x4){0.f,0.f,0.f,0.f};
    for (int kt = 0; kt < 8; ++kt) {
        #pragma unroll
        for (int i = 0; i < 8; ++i) {
            int f4 = i*256 + tid;
            int r  = f4 >> 4;
            int kp = (f4 & 15) * 4;
            f32x4 v = *(const f32x4*)(x + (size_t)(m0+r)*DD + kt*64 + kp);
            float2 st = *(const float2*)(stats + (size_t)(m0+r)*2);
            s16x4 h;
            h[0] = f2bf((v[0]-st.x)*st.y);
            h[1] = f2bf((v[1]-st.x)*st.y);
            h[2] = f2bf((v[2]-st.x)*st.y);
            h[3] = f2bf((v[3]-st.x)*st.y);
            *(s16x4*)(&As[r][kp]) = h;
        }
        #pragma unroll
        for (int i = 0; i < 4; ++i) {
            int f8 = i*256 + tid;
            int r  = f8 >> 3;
            int kp = (f8 & 7) * 8;
            *(s16x8*)(&Bs[r][kp]) = *(const s16x8*)(gateT + (size_t)(n0+r)*DD + kt*64 + kp);
        }
        __syncthreads();
        #pragma unroll
        for (int kk = 0; kk < 2; ++kk) {
            s16x8 af[4], bfr[4];
            #pragma unroll
            for (int mi=0;mi<4;mi++)
                af[mi] = *(const s16x8*)(&As[wr*64 + mi*16 + l15][kk*32 + lg*8]);
            #pragma unroll
            for (int ni=0;ni<4;ni++)
                bfr[ni] = *(const s16x8*)(&Bs[wc*64 + ni*16 + l15][kk*32 + lg*8]);
            #pragma unroll
            for (int mi=0;mi<4;mi++)
              #pragma unroll
              for (int ni=0;ni<4;ni++)
                acc[mi][ni] = __builtin_amdgcn_mfma_f32_16x16x32_bf16(af[mi], bfr[ni], acc[mi][ni], 0,0,0);
        }
        __syncthreads();
    }
    #pragma unroll
    for (int mi=0;mi<4;mi++)
      #pragma unroll
      for (int ni=0;ni<4;ni++) {
        int row0 = m0 + wr*64 + mi*16 + lg*4;
        int col  = n0 + wc*64 + ni*16 + l15;
        s16x4 h4;
        #pragma unroll
        for (int r=0;r<4;r++) h4[r] = f2bf(acc[mi][ni][r]);
        #pragma unroll
        for (int r=0;r<4;r++) qkv[(size_t)(row0+r)*DD + col] = h4[r];
        int b2 = row0 >> 10, t0 = row0 & 1023;
        *(s16x4*)(qkvT + (size_t)b2*DD*TT + (size_t)col*TT + t0) = h4;
      }
}

// ---- flash attention: 4 waves / 64 q-rows, K dbuf in LDS, V direct-from-global ----
// LDS = 2x32KB (K dbuf) + 16KB (Sx) = 80KB -> 2 blocks/CU (two barrier domains).
// Stage K[t+1] at tile TOP (drained by end-of-tile vmcnt: full tile of cover).
__global__ __launch_bounds__(256,2) void k_attn(const short* __restrict__ qkv,
                                                const short* __restrict__ qkvT,
                                                const float* __restrict__ xin,
                                                float* __restrict__ out) {
    __shared__ __align__(16) short Kt[2][16384];   // [buf][32 kv][512 d], slot^=(kv&7)
    __shared__ __align__(16) float Sx[4][1024];    // partial-S exchange, swizzled
    const float scale = 0.044194173824159216f;
    int bid = blockIdx.x;
    int xcd = bid & 7, k = bid >> 3;               // 96 blocks per XCD slice
    int batch = 6*xcd + (k % 6);
    int qj = 15 - (k / 6);                         // heavy q-groups dispatched first
    int tid = threadIdx.x, lane = tid & 63, w = tid >> 6;
    int s = w >> 1, dh = w & 1;
    int l31 = lane & 31, lh = lane >> 5;
    int qb = qj*64 + s*32;
    int qglob = qb + l31;
    const short* gq  = qkv  + (size_t)batch*TT*DD;
    const short* gvt = qkvT + (size_t)batch*DD*TT;

    // Q fragments (swapped QK^T B-operand): lane holds q=l31, its d-half
    s16x8 qf[16];
    {
        const short* qrow = gq + (size_t)qglob*DD + dh*256 + lh*8;
        #pragma unroll
        for (int kc=0;kc<16;kc++) qf[kc] = *(const s16x8*)(qrow + kc*16);
    }
    f32x16 o[8];
    #pragma unroll
    for (int m=0;m<8;m++)
        #pragma unroll
        for (int r=0;r<16;r++) o[m][r] = 0.f;
    float m_run = -1e30f, l_run = 0.f;
    int ntile = 2*(qj+1);

    auto stageK = [&](int t, int c) {
        const char* ksrc = (const char*)(gq + (size_t)(t*32)*DD);
        char* kdst = (char*)&Kt[c][0];
        #pragma unroll
        for (int i=0;i<8;i++){
            int o16 = i*4096 + w*1024;          // wave-uniform LDS offset
            int ol  = o16 + (lane<<4);
            int go  = ol ^ (((ol>>10)&7)<<4);   // pre-swizzled global source (K)
            gll16(ksrc + go, kdst + o16);
        }
    };

    stageK(0, 0);
    __syncthreads();
    for (int t = 0; t < ntile; ++t) {
        int kv0 = t*32;
        if (t + 1 < ntile) stageK(t+1, (t+1)&1);   // buf free since BAR_t of t-1
        bool act = (kv0 <= qb + 31);               // wave-uniform: skip masked tile
        const char* kbase = (const char*)&Kt[t&1][0];
        f32x16 sA, sB;
        if (act) {
            #pragma unroll
            for (int r=0;r<16;r++){ sA[r]=0.f; sB[r]=0.f; }
            #pragma unroll
            for (int kc=0;kc<8;kc++) {             // two independent chains
                int b0 = (dh*512 + (2*kc)*32 + lh*16) ^ ((l31 & 7) << 4);
                int b1 = (dh*512 + (2*kc+1)*32 + lh*16) ^ ((l31 & 7) << 4);
                s16x8 kf0 = *(const s16x8*)(kbase + l31*1024 + b0);
                s16x8 kf1 = *(const s16x8*)(kbase + l31*1024 + b1);
                sA = __builtin_amdgcn_mfma_f32_32x32x16_bf16(kf0, qf[2*kc],   sA, 0,0,0);
                sB = __builtin_amdgcn_mfma_f32_32x32x16_bf16(kf1, qf[2*kc+1], sB, 0,0,0);
            }
            float* sw = &Sx[w][0];
            int sl = (lane>>1)&3;
            #pragma unroll
            for (int c=0;c<4;c++){
                f32x4 ch = (f32x4){sA[4*c]+sB[4*c], sA[4*c+1]+sB[4*c+1],
                                   sA[4*c+2]+sB[4*c+2], sA[4*c+3]+sB[4*c+3]};
                *(f32x4*)(sw + lane*16 + ((c ^ sl)<<2)) = ch;
            }
        }
        // first PV V-loads issued pre-barrier: L2 latency hides under softmax
        const short* pv = gvt + (size_t)(dh*256 + l31)*TT + kv0 + lh*8;
        s16x8 vf0, vf1;
        if (act) {
            vf0 = *(const s16x8*)(pv);
            vf1 = *(const s16x8*)(pv + 16);
        }
        // BAR_x: Sx visible (LDS only; K[t+1] staging stays in flight)
        asm volatile("s_waitcnt lgkmcnt(0)\n\ts_barrier" ::: "memory");
        if (act) {
            float p[16]; float mx = -1e30f;
            {
                const float* sr = &Sx[w^1][0];
                int sl = (lane>>1)&3;
                #pragma unroll
                for (int c=0;c<4;c++){
                    f32x4 pc = *(const f32x4*)(sr + lane*16 + ((c ^ sl)<<2));
                    #pragma unroll
                    for (int jj=0;jj<4;jj++){
                        int r = 4*c + jj;
                        float v = (sA[r]+sB[r] + pc[jj]) * scale;
                        int kvr = kv0 + jj + 8*c + 4*lh;
                        if (kvr > qglob) v = -1e30f;
                        p[r] = v;
                        mx = fmaxf(mx, v);
                    }
                }
            }
            mx = fmaxf(mx, __shfl_xor(mx, 32));
            if (__any(mx > m_run)) {
                float mn = fmaxf(m_run, mx);
                float alpha = __expf(m_run - mn);
                m_run = mn;
                l_run *= alpha;
                #pragma unroll
                for (int m=0;m<8;m++)
                    #pragma unroll
                    for (int r=0;r<16;r++) o[m][r] *= alpha;
            }
            float ls = 0.f;
            #pragma unroll
            for (int r=0;r<16;r++){ p[r] = __expf(p[r] - m_run); ls += p[r]; }
            ls += __shfl_xor(ls, 32);
            l_run += ls;
            s16x8 pb[2];
            #pragma unroll
            for (int km=0;km<2;km++){
                int b = 8*km;
                unsigned X0 = pk_bf16(p[b+0], p[b+1]);
                unsigned X1 = pk_bf16(p[b+2], p[b+3]);
                unsigned Y0 = pk_bf16(p[b+4], p[b+5]);
                unsigned Y1 = pk_bf16(p[b+6], p[b+7]);
                asm volatile("v_permlane32_swap_b32 %0, %1" : "+v"(X0), "+v"(Y0));
                asm volatile("v_permlane32_swap_b32 %0, %1" : "+v"(X1), "+v"(Y1));
                union { unsigned u[4]; s16x8 v; } pu;
                pu.u[0] = X0; pu.u[1] = X1; pu.u[2] = Y0; pu.u[3] = Y1;
                pb[km] = pu.v;
            }
            // PV: V^T rows straight from global (L2), 2-deep load pipeline
            __builtin_amdgcn_s_setprio(1);
            #pragma unroll
            for (int m=0;m<8;m++){
                s16x8 nf0, nf1;
                if (m < 7) {
                    const short* pn = pv + (size_t)(m+1)*32*TT;
                    nf0 = *(const s16x8*)(pn);
                    nf1 = *(const s16x8*)(pn + 16);
                }
                o[m] = __builtin_amdgcn_mfma_f32_32x32x16_bf16(vf0, pb[0], o[m], 0,0,0);
                o[m] = __builtin_amdgcn_mfma_f32_32x32x16_bf16(vf1, pb[1], o[m], 0,0,0);
                vf0 = nf0; vf1 = nf1;
            }
            __builtin_amdgcn_s_setprio(0);
        }
        // BAR_t: K[t+1] staged (issued a full tile ago), all reads of buf t done
        asm volatile("s_waitcnt vmcnt(0) lgkmcnt(0)\n\ts_barrier" ::: "memory");
    }
    // epilogue: O^T -> transpose via LDS (Kt[0]: 4 waves x 4.5KB = 18KB) -> stores
    float inv = 1.0f / l_run;
    #pragma unroll
    for (int m=0;m<8;m++)
        #pragma unroll
        for (int r=0;r<16;r++) o[m][r] *= inv;
    float* T = (float*)&Kt[0][0] + w*1152;         // 32 x 36 f32 per wave
    #pragma unroll
    for (int m=0;m<8;m++){
        #pragma unroll
        for (int r=0;r<16;r++){
            int dloc = (r&3) + 8*(r>>2) + 4*lh;
            T[l31*36 + dloc] = o[m][r];
        }
        __builtin_amdgcn_s_waitcnt(0);
        #pragma unroll
        for (int p2=0;p2<4;p2++){
            int qr = p2*8 + (lane>>3);
            f32x4 tv = *(const f32x4*)(T + qr*36 + (lane&7)*4);
            size_t gofs = ((size_t)batch*TT + qb + qr)*DD + dh*256 + m*32 + (lane&7)*4;
            f32x4 xi = *(const f32x4*)(xin + gofs);
            *(f32x4*)(out + gofs) = tv + xi;
        }
        __builtin_amdgcn_s_waitcnt(0);
    }
}

// ---------------- cross-cell mix + tanh + pulse (in place on d_out) ----------------
__device__ __forceinline__ float tanh_fast(float x) {
    float e = __expf(2.0f*x);
    return 1.0f - __fdividef(2.0f, e + 1.0f);
}

__global__ __launch_bounds__(256) void k_post(float* __restrict__ xo,
                                              const float* __restrict__ inhibit,
                                              const float* __restrict__ phases,
                                              const float* __restrict__ ambition) {
    int idx = blockIdx.x*256 + threadIdx.x;
    int b = idx >> 17;
    int rem = idx & 131071;
    size_t base = (size_t)b*6*TT*DD + (size_t)(rem >> 7)*DD + (size_t)(rem & 127)*4;
    f32x4 v[6];
    #pragma unroll
    for (int c=0;c<6;c++) v[c] = *(const f32x4*)(xo + base + (size_t)c*TT*DD);
    float inh[36];
    #pragma unroll
    for (int i=0;i<36;i++) inh[i] = inhibit[i];
    #pragma unroll
    for (int k=0;k<6;k++){
        float c0=0.f, c1=0.f, c2=0.f, c3=0.f;
        #pragma unroll
        for (int c=0;c<6;c++){
            float wv = inh[c*6+k];
            c0 += v[c][0]*wv; c1 += v[c][1]*wv;
            c2 += v[c][2]*wv; c3 += v[c][3]*wv;
        }
        float a = ambition[k], ph = phases[k];
        float x0 = v[k][0] + tanh_fast(c0);
        float x1 = v[k][1] + tanh_fast(c1);
        float x2 = v[k][2] + tanh_fast(c2);
        float x3 = v[k][3] + tanh_fast(c3);
        f32x4 ov;
        ov[0] = x0 + __sinf(x0*a + ph)*0.02f;
        ov[1] = x1 + __sinf(x1*a + ph)*0.02f;
        ov[2] = x2 + __sinf(x2*a + ph)*0.02f;
        ov[3] = x3 + __sinf(x3*a + ph)*0.02f;
        *(f32x4*)(xo + base + (size_t)k*TT*DD) = ov;
    }
}

extern "C" void kernel_launch(void* const* d_in, const int* in_sizes, int n_in,
                              void* d_out, int out_size, void* d_ws, size_t ws_size,
                              hipStream_t stream) {
    (void)in_sizes; (void)n_in; (void)out_size; (void)ws_size;
    const float* x        = (const float*)d_in[0];
    const float* gate     = (const float*)d_in[2];
    const float* inhibit  = (const float*)d_in[3];
    const float* phases   = (const float*)d_in[4];
    const float* ambition = (const float*)d_in[5];
    float* out = (float*)d_out;
    char* ws = (char*)d_ws;
    short* qkv   = (short*)(ws);                    // 50331648 B
    short* qkvT  = (short*)(ws + 50331648);         // 50331648 B
    float* stats = (float*)(ws + 100663296);        // 393216 B
    short* gateT = (short*)(ws + 101056512);        // 524288 B

    k_ln_stats <<<dim3(12288), dim3(256), 0, stream>>>(x, stats);
    k_gate_t   <<<dim3(64),    dim3(256), 0, stream>>>(gate, gateT);
    k_qkv      <<<dim3(1536),  dim3(256), 0, stream>>>(x, stats, gateT, qkv, qkvT);
    k_attn     <<<dim3(768),   dim3(256), 0, stream>>>(qkv, qkvT, x, out);
    k_post     <<<dim3(4096),  dim3(256), 0, stream>>>(out, inhibit, phases, ambition);
}

// Round 8
// 383.468 us; speedup vs baseline: 1.0645x; 1.0645x over previous
//
#include <hip/hip_runtime.h>
#include <math.h>

typedef __attribute__((ext_vector_type(4))) float f32x4;
typedef __attribute__((ext_vector_type(16))) float f32x16;
typedef __attribute__((ext_vector_type(8))) short s16x8;
typedef __attribute__((ext_vector_type(4))) short s16x4;

#define DD 512
#define TT 1024
#define NB 48

__device__ __forceinline__ short f2bf(float f) {
    union { float f; unsigned u; } v; v.f = f;
    unsigned r = v.u + 0x7fffu + ((v.u >> 16) & 1u);
    return (short)(r >> 16);
}

__device__ __forceinline__ void gll16(const void* g, void* l) {
    __builtin_amdgcn_global_load_lds(
        (const __attribute__((address_space(1))) unsigned int*)g,
        (__attribute__((address_space(3))) unsigned int*)l, 16, 0, 0);
}

__device__ __forceinline__ unsigned pk_bf16(float lo, float hi) {
    unsigned r;
    asm("v_cvt_pk_bf16_f32 %0, %1, %2" : "=v"(r) : "v"(lo), "v"(hi));
    return r;
}

// ---------------- LayerNorm stats: one wave per row ----------------
__global__ __launch_bounds__(256) void k_ln_stats(const float* __restrict__ x,
                                                  float* __restrict__ stats) {
    int row = blockIdx.x * 4 + (threadIdx.x >> 6);
    int lane = threadIdx.x & 63;
    const float* p = x + (size_t)row * DD + lane * 8;
    f32x4 a = *(const f32x4*)p;
    f32x4 b = *(const f32x4*)(p + 4);
    float s  = a[0]+a[1]+a[2]+a[3]+b[0]+b[1]+b[2]+b[3];
    float ss = a[0]*a[0]+a[1]*a[1]+a[2]*a[2]+a[3]*a[3]
             + b[0]*b[0]+b[1]*b[1]+b[2]*b[2]+b[3]*b[3];
    #pragma unroll
    for (int off = 32; off >= 1; off >>= 1) {
        s  += __shfl_xor(s, off);
        ss += __shfl_xor(ss, off);
    }
    if (lane == 0) {
        float mu  = s * (1.0f/DD);
        float var = ss * (1.0f/DD) - mu*mu;
        float2 st; st.x = mu; st.y = rsqrtf(var + 1e-5f);
        *(float2*)(stats + (size_t)row*2) = st;
    }
}

// ---------------- gate -> gateT (bf16) ----------------
__global__ __launch_bounds__(256) void k_gate_t(const float* __restrict__ gate,
                                                short* __restrict__ gateT) {
    __shared__ float tile[64][65];
    int k0 = (blockIdx.x >> 3) * 64;
    int n0 = (blockIdx.x & 7) * 64;
    int tid = threadIdx.x;
    #pragma unroll
    for (int i = 0; i < 16; ++i) {
        int f = i*256 + tid;
        int r = f >> 6, c = f & 63;
        tile[r][c] = gate[(size_t)(k0+r)*DD + n0 + c];
    }
    __syncthreads();
    #pragma unroll
    for (int i = 0; i < 16; ++i) {
        int f = i*256 + tid;
        int r = f >> 6, c = f & 63;
        gateT[(size_t)(n0+r)*DD + k0 + c] = f2bf(tile[c][r]);
    }
}

// ------- qkv = LN(x) @ gate  (bf16 MFMA, 128x128 tile, BK=64), also writes qkvT -------
__global__ __launch_bounds__(256,2) void k_qkv(const float* __restrict__ x,
                                               const float* __restrict__ stats,
                                               const short* __restrict__ gateT,
                                               short* __restrict__ qkv,
                                               short* __restrict__ qkvT) {
    __shared__ __align__(16) short As[128][72];
    __shared__ __align__(16) short Bs[128][72];
    int m0 = (blockIdx.x >> 2) * 128;
    int n0 = (blockIdx.x & 3) * 128;
    int tid = threadIdx.x, lane = tid & 63, w = tid >> 6;
    int wr = w >> 1, wc = w & 1;
    int l15 = lane & 15, lg = lane >> 4;
    f32x4 acc[4][4];
    #pragma unroll
    for (int i=0;i<4;i++)
      #pragma unroll
      for (int j=0;j<4;j++)
        acc[i][j] = (f32x4){0.f,0.f,0.f,0.f};
    for (int kt = 0; kt < 8; ++kt) {
        #pragma unroll
        for (int i = 0; i < 8; ++i) {
            int f4 = i*256 + tid;
            int r  = f4 >> 4;
            int kp = (f4 & 15) * 4;
            f32x4 v = *(const f32x4*)(x + (size_t)(m0+r)*DD + kt*64 + kp);
            float2 st = *(const float2*)(stats + (size_t)(m0+r)*2);
            s16x4 h;
            h[0] = f2bf((v[0]-st.x)*st.y);
            h[1] = f2bf((v[1]-st.x)*st.y);
            h[2] = f2bf((v[2]-st.x)*st.y);
            h[3] = f2bf((v[3]-st.x)*st.y);
            *(s16x4*)(&As[r][kp]) = h;
        }
        #pragma unroll
        for (int i = 0; i < 4; ++i) {
            int f8 = i*256 + tid;
            int r  = f8 >> 3;
            int kp = (f8 & 7) * 8;
            *(s16x8*)(&Bs[r][kp]) = *(const s16x8*)(gateT + (size_t)(n0+r)*DD + kt*64 + kp);
        }
        __syncthreads();
        #pragma unroll
        for (int kk = 0; kk < 2; ++kk) {
            s16x8 af[4], bfr[4];
            #pragma unroll
            for (int mi=0;mi<4;mi++)
                af[mi] = *(const s16x8*)(&As[wr*64 + mi*16 + l15][kk*32 + lg*8]);
            #pragma unroll
            for (int ni=0;ni<4;ni++)
                bfr[ni] = *(const s16x8*)(&Bs[wc*64 + ni*16 + l15][kk*32 + lg*8]);
            #pragma unroll
            for (int mi=0;mi<4;mi++)
              #pragma unroll
              for (int ni=0;ni<4;ni++)
                acc[mi][ni] = __builtin_amdgcn_mfma_f32_16x16x32_bf16(af[mi], bfr[ni], acc[mi][ni], 0,0,0);
        }
        __syncthreads();
    }
    #pragma unroll
    for (int mi=0;mi<4;mi++)
      #pragma unroll
      for (int ni=0;ni<4;ni++) {
        int row0 = m0 + wr*64 + mi*16 + lg*4;
        int col  = n0 + wc*64 + ni*16 + l15;
        s16x4 h4;
        #pragma unroll
        for (int r=0;r<4;r++) h4[r] = f2bf(acc[mi][ni][r]);
        #pragma unroll
        for (int r=0;r<4;r++) qkv[(size_t)(row0+r)*DD + col] = h4[r];
        int b2 = row0 >> 10, t0 = row0 & 1023;
        *(s16x4*)(qkvT + (size_t)b2*DD*TT + (size_t)col*TT + t0) = h4;
      }
}

// ---- flash attention: 8 waves, 128q/job, swapped 32x32 MFMA, in-register softmax ----
// r5 structure (190us) + balanced static 2-job schedule (256 blocks, makespan 8 units)
// + wave-uniform masked-tile skip. wave w: q-subtile s=w&3, d-half dh=w>>2.
__global__ __launch_bounds__(512,2) void k_attn(const short* __restrict__ qkv,
                                                const short* __restrict__ qkvT,
                                                const float* __restrict__ xin,
                                                float* __restrict__ out) {
    __shared__ __align__(16) short Kt[2][16384];   // [buf][32 kv][512 d] rows 1KB, slot^=(kv&7)
    __shared__ __align__(16) short Vt[2][16384];   // [buf][512 d][32 kv] rows 64B, slot^=((d>>1)&3)
    __shared__ __align__(16) float Sx[8][1024];    // per-wave partial-S exchange, swizzled
    const float scale = 0.044194173824159216f;
    int bid = blockIdx.x;
    // balanced job table: sizes (qg+1); singles 8,7,6; pairs 6+1,5+2,4+3,1+1
    int b1, g1, b2 = -1, g2 = -1;
    if (bid < 48)       { b1 = bid;            g1 = 7; }
    else if (bid < 96)  { b1 = bid-48;         g1 = 6; }
    else if (bid < 128) { b1 = bid-96;         g1 = 5; }
    else if (bid < 144) { b1 = 32+(bid-128);   g1 = 5; b2 = bid-128;       g2 = 0; }
    else if (bid < 192) { b1 = bid-144;        g1 = 4; b2 = bid-144;       g2 = 1; }
    else if (bid < 240) { b1 = bid-192;        g1 = 3; b2 = bid-192;       g2 = 2; }
    else                { b1 = 16+2*(bid-240); g1 = 0; b2 = 17+2*(bid-240); g2 = 0; }
    int tid = threadIdx.x, lane = tid & 63, w = tid >> 6;
    int s = w & 3, dh = w >> 2;
    int l31 = lane & 31, lh = lane >> 5;

    for (int job = 0; job < 2; ++job) {
        int batch = job ? b2 : b1;
        int qg    = job ? g2 : g1;
        if (batch < 0) break;
        int qb = qg*128 + s*32;
        int qglob = qb + l31;
        const short* gq  = qkv  + (size_t)batch*TT*DD;
        const short* gvt = qkvT + (size_t)batch*DD*TT;

        // Q fragments (swapped QK^T B-operand): lane holds q=l31, its d-half
        s16x8 qf[16];
        {
            const short* qrow = gq + (size_t)qglob*DD + dh*256 + lh*8;
            #pragma unroll
            for (int kc=0;kc<16;kc++) qf[kc] = *(const s16x8*)(qrow + kc*16);
        }
        f32x16 o[8];
        #pragma unroll
        for (int m=0;m<8;m++)
            #pragma unroll
            for (int r=0;r<16;r++) o[m][r] = 0.f;
        float m_run = -1e30f, l_run = 0.f;
        int ntile = 4*(qg+1);

        auto stage = [&](int j, int c) {
            int kv0 = j*32;
            const char* ksrc = (const char*)(gq + (size_t)kv0*DD);
            char* kdst = (char*)&Kt[c][0];
            #pragma unroll
            for (int i=0;i<4;i++){
                int o16 = i*8192 + w*1024;          // wave-uniform LDS offset
                int ol  = o16 + (lane<<4);
                int go  = ol ^ (((ol>>10)&7)<<4);   // pre-swizzled global source (K)
                gll16(ksrc + go, kdst + o16);
            }
            const char* vsrc = (const char*)gvt;
            char* vdst = (char*)&Vt[c][0];
            #pragma unroll
            for (int i=0;i<4;i++){
                int o16 = i*8192 + w*1024;
                int ol  = o16 + (lane<<4);
                int d   = ol >> 6, c2 = ol & 63;
                int c2s = c2 ^ (((d>>1)&3)<<4);     // pre-swizzled global source (V)
                gll16(vsrc + (size_t)d*2048 + (size_t)kv0*2 + c2s, vdst + o16);
            }
        };

        __syncthreads();   // protect prior job's epilogue scratch (no-op for job 0)
        stage(0, 0);
        __syncthreads();
        for (int kj = 0; kj < ntile; ++kj) {
            int cur = kj & 1;
            int kv0 = kj*32;
            if (kj + 1 < ntile) stage(kj+1, (kj+1)&1);
            bool act = (kv0 <= qb + 31);            // wave-uniform masked-tile skip
            const char* kbase = (const char*)&Kt[cur][0];
            const char* vbase = (const char*)&Vt[cur][0];
            f32x16 sT;
            if (act) {
                #pragma unroll
                for (int r=0;r<16;r++) sT[r] = 0.f;
                #pragma unroll
                for (int kc=0;kc<16;kc++) {
                    int boff = (dh*512 + kc*32 + lh*16) ^ ((l31 & 7) << 4);
                    s16x8 kf = *(const s16x8*)(kbase + l31*1024 + boff);
                    sT = __builtin_amdgcn_mfma_f32_32x32x16_bf16(kf, qf[kc], sT, 0,0,0);
                }
                float* sw = &Sx[w][0];
                int sl = (lane>>1)&3;
                #pragma unroll
                for (int c=0;c<4;c++){
                    f32x4 ch = (f32x4){sT[4*c],sT[4*c+1],sT[4*c+2],sT[4*c+3]};
                    *(f32x4*)(sw + lane*16 + ((c ^ sl)<<2)) = ch;
                }
            }
            asm volatile("s_waitcnt lgkmcnt(0)\n\ts_barrier" ::: "memory");
            if (act) {
                float p[16]; float mx = -1e30f;
                {
                    const float* sr = &Sx[w^4][0];
                    int sl = (lane>>1)&3;
                    #pragma unroll
                    for (int c=0;c<4;c++){
                        f32x4 pc = *(const f32x4*)(sr + lane*16 + ((c ^ sl)<<2));
                        #pragma unroll
                        for (int j=0;j<4;j++){
                            int r = 4*c + j;
                            float v = (sT[r] + pc[j]) * scale;
                            int kvr = kv0 + j + 8*c + 4*lh;
                            if (kvr > qglob) v = -1e30f;
                            p[r] = v;
                            mx = fmaxf(mx, v);
                        }
                    }
                }
                mx = fmaxf(mx, __shfl_xor(mx, 32));
                if (__any(mx > m_run)) {
                    float mn = fmaxf(m_run, mx);
                    float alpha = __expf(m_run - mn);
                    m_run = mn;
                    l_run *= alpha;
                    #pragma unroll
                    for (int m=0;m<8;m++)
                        #pragma unroll
                        for (int r=0;r<16;r++) o[m][r] *= alpha;
                }
                float ls = 0.f;
                #pragma unroll
                for (int r=0;r<16;r++){ p[r] = __expf(p[r] - m_run); ls += p[r]; }
                ls += __shfl_xor(ls, 32);
                l_run += ls;
                // pack P -> B-frags in-register (cvt_pk + permlane32_swap)
                s16x8 pb[2];
                #pragma unroll
                for (int km=0;km<2;km++){
                    int b = 8*km;
                    unsigned X0 = pk_bf16(p[b+0], p[b+1]);
                    unsigned X1 = pk_bf16(p[b+2], p[b+3]);
                    unsigned Y0 = pk_bf16(p[b+4], p[b+5]);
                    unsigned Y1 = pk_bf16(p[b+6], p[b+7]);
                    asm volatile("v_permlane32_swap_b32 %0, %1" : "+v"(X0), "+v"(Y0));
                    asm volatile("v_permlane32_swap_b32 %0, %1" : "+v"(X1), "+v"(Y1));
                    union { unsigned u[4]; s16x8 v; } pu;
                    pu.u[0] = X0; pu.u[1] = X1; pu.u[2] = Y0; pu.u[3] = Y1;
                    pb[km] = pu.v;
                }
                // PV swapped: O^T += V^T-frag x P-frag
                __builtin_amdgcn_s_setprio(1);
                #pragma unroll
                for (int m=0;m<8;m++){
                    int row = dh*256 + m*32 + l31;
                    #pragma unroll
                    for (int km=0;km<2;km++){
                        int boff = ((km*32 + lh*16) ^ (((row>>1)&3)<<4));
                        s16x8 vf = *(const s16x8*)(vbase + (row<<6) + boff);
                        o[m] = __builtin_amdgcn_mfma_f32_32x32x16_bf16(vf, pb[km], o[m], 0,0,0);
                    }
                }
                __builtin_amdgcn_s_setprio(0);
            }
            __syncthreads();   // next-tile stage drained; all waves done with cur
        }
        // epilogue: O^T -> transpose via LDS (reuse Kt region) -> coalesced stores
        float inv = 1.0f / l_run;
        #pragma unroll
        for (int m=0;m<8;m++)
            #pragma unroll
            for (int r=0;r<16;r++) o[m][r] *= inv;
        float* T = (float*)&Kt[0][0] + w*1152;   // 32 x 36 f32 per wave
        #pragma unroll
        for (int m=0;m<8;m++){
            #pragma unroll
            for (int r=0;r<16;r++){
                int dloc = (r&3) + 8*(r>>2) + 4*lh;
                T[l31*36 + dloc] = o[m][r];
            }
            __builtin_amdgcn_s_waitcnt(0);  // lgkmcnt(0): writes visible to own wave
            #pragma unroll
            for (int p2=0;p2<4;p2++){
                int qr = p2*8 + (lane>>3);
                f32x4 t = *(const f32x4*)(T + qr*36 + (lane&7)*4);
                size_t gofs = ((size_t)batch*TT + qb + qr)*DD + dh*256 + m*32 + (lane&7)*4;
                f32x4 xi = *(const f32x4*)(xin + gofs);
                *(f32x4*)(out + gofs) = t + xi;
            }
            __builtin_amdgcn_s_waitcnt(0);  // reads done before next m overwrites T
        }
    }
}

// ---------------- cross-cell mix + tanh + pulse (in place on d_out) ----------------
__device__ __forceinline__ float tanh_fast(float x) {
    float e = __expf(2.0f*x);
    return 1.0f - __fdividef(2.0f, e + 1.0f);
}

__global__ __launch_bounds__(256) void k_post(float* __restrict__ xo,
                                              const float* __restrict__ inhibit,
                                              const float* __restrict__ phases,
                                              const float* __restrict__ ambition) {
    int idx = blockIdx.x*256 + threadIdx.x;
    int b = idx >> 17;
    int rem = idx & 131071;
    size_t base = (size_t)b*6*TT*DD + (size_t)(rem >> 7)*DD + (size_t)(rem & 127)*4;
    f32x4 v[6];
    #pragma unroll
    for (int c=0;c<6;c++) v[c] = *(const f32x4*)(xo + base + (size_t)c*TT*DD);
    float inh[36];
    #pragma unroll
    for (int i=0;i<36;i++) inh[i] = inhibit[i];
    #pragma unroll
    for (int k=0;k<6;k++){
        float c0=0.f, c1=0.f, c2=0.f, c3=0.f;
        #pragma unroll
        for (int c=0;c<6;c++){
            float wv = inh[c*6+k];
            c0 += v[c][0]*wv; c1 += v[c][1]*wv;
            c2 += v[c][2]*wv; c3 += v[c][3]*wv;
        }
        float a = ambition[k], ph = phases[k];
        float x0 = v[k][0] + tanh_fast(c0);
        float x1 = v[k][1] + tanh_fast(c1);
        float x2 = v[k][2] + tanh_fast(c2);
        float x3 = v[k][3] + tanh_fast(c3);
        f32x4 ov;
        ov[0] = x0 + __sinf(x0*a + ph)*0.02f;
        ov[1] = x1 + __sinf(x1*a + ph)*0.02f;
        ov[2] = x2 + __sinf(x2*a + ph)*0.02f;
        ov[3] = x3 + __sinf(x3*a + ph)*0.02f;
        *(f32x4*)(xo + base + (size_t)k*TT*DD) = ov;
    }
}

extern "C" void kernel_launch(void* const* d_in, const int* in_sizes, int n_in,
                              void* d_out, int out_size, void* d_ws, size_t ws_size,
                              hipStream_t stream) {
    (void)in_sizes; (void)n_in; (void)out_size; (void)ws_size;
    const float* x        = (const float*)d_in[0];
    const float* gate     = (const float*)d_in[2];
    const float* inhibit  = (const float*)d_in[3];
    const float* phases   = (const float*)d_in[4];
    const float* ambition = (const float*)d_in[5];
    float* out = (float*)d_out;
    char* ws = (char*)d_ws;
    short* qkv   = (short*)(ws);                    // 50331648 B
    short* qkvT  = (short*)(ws + 50331648);         // 50331648 B
    float* stats = (float*)(ws + 100663296);        // 393216 B
    short* gateT = (short*)(ws + 101056512);        // 524288 B

    k_ln_stats <<<dim3(12288), dim3(256), 0, stream>>>(x, stats);
    k_gate_t   <<<dim3(64),    dim3(256), 0, stream>>>(gate, gateT);
    k_qkv      <<<dim3(1536),  dim3(256), 0, stream>>>(x, stats, gateT, qkv, qkvT);
    k_attn     <<<dim3(256),   dim3(512), 0, stream>>>(qkv, qkvT, x, out);
    k_post     <<<dim3(4096),  dim3(256), 0, stream>>>(out, inhibit, phases, ambition);
}

// Round 9
// 280.770 us; speedup vs baseline: 1.4539x; 1.3658x over previous
//
#include <hip/hip_runtime.h>
#include <math.h>

typedef __attribute__((ext_vector_type(4))) float f32x4;
typedef __attribute__((ext_vector_type(16))) float f32x16;
typedef __attribute__((ext_vector_type(8))) short s16x8;
typedef __attribute__((ext_vector_type(4))) short s16x4;

#define DD 512
#define TT 1024
#define NB 48

__device__ __forceinline__ short f2bf(float f) {
    union { float f; unsigned u; } v; v.f = f;
    unsigned r = v.u + 0x7fffu + ((v.u >> 16) & 1u);
    return (short)(r >> 16);
}

__device__ __forceinline__ void gll16(const void* g, void* l) {
    __builtin_amdgcn_global_load_lds(
        (const __attribute__((address_space(1))) unsigned int*)g,
        (__attribute__((address_space(3))) unsigned int*)l, 16, 0, 0);
}

__device__ __forceinline__ unsigned pk_bf16(float lo, float hi) {
    unsigned r;
    asm("v_cvt_pk_bf16_f32 %0, %1, %2" : "=v"(r) : "v"(lo), "v"(hi));
    return r;
}

// ---------------- LayerNorm stats: one wave per row ----------------
__global__ __launch_bounds__(256) void k_ln_stats(const float* __restrict__ x,
                                                  float* __restrict__ stats) {
    int row = blockIdx.x * 4 + (threadIdx.x >> 6);
    int lane = threadIdx.x & 63;
    const float* p = x + (size_t)row * DD + lane * 8;
    f32x4 a = *(const f32x4*)p;
    f32x4 b = *(const f32x4*)(p + 4);
    float s  = a[0]+a[1]+a[2]+a[3]+b[0]+b[1]+b[2]+b[3];
    float ss = a[0]*a[0]+a[1]*a[1]+a[2]*a[2]+a[3]*a[3]
             + b[0]*b[0]+b[1]*b[1]+b[2]*b[2]+b[3]*b[3];
    #pragma unroll
    for (int off = 32; off >= 1; off >>= 1) {
        s  += __shfl_xor(s, off);
        ss += __shfl_xor(ss, off);
    }
    if (lane == 0) {
        float mu  = s * (1.0f/DD);
        float var = ss * (1.0f/DD) - mu*mu;
        float2 st; st.x = mu; st.y = rsqrtf(var + 1e-5f);
        *(float2*)(stats + (size_t)row*2) = st;
    }
}

// ---------------- gate -> gateT (bf16) ----------------
__global__ __launch_bounds__(256) void k_gate_t(const float* __restrict__ gate,
                                                short* __restrict__ gateT) {
    __shared__ float tile[64][65];
    int k0 = (blockIdx.x >> 3) * 64;
    int n0 = (blockIdx.x & 7) * 64;
    int tid = threadIdx.x;
    #pragma unroll
    for (int i = 0; i < 16; ++i) {
        int f = i*256 + tid;
        int r = f >> 6, c = f & 63;
        tile[r][c] = gate[(size_t)(k0+r)*DD + n0 + c];
    }
    __syncthreads();
    #pragma unroll
    for (int i = 0; i < 16; ++i) {
        int f = i*256 + tid;
        int r = f >> 6, c = f & 63;
        gateT[(size_t)(n0+r)*DD + k0 + c] = f2bf(tile[c][r]);
    }
}

// ------- qkv = LN(x) @ gate  (bf16 MFMA, 128x128 tile, BK=64), also writes qkvT -------
__global__ __launch_bounds__(256,2) void k_qkv(const float* __restrict__ x,
                                               const float* __restrict__ stats,
                                               const short* __restrict__ gateT,
                                               short* __restrict__ qkv,
                                               short* __restrict__ qkvT) {
    __shared__ __align__(16) short As[128][72];
    __shared__ __align__(16) short Bs[128][72];
    int m0 = (blockIdx.x >> 2) * 128;
    int n0 = (blockIdx.x & 3) * 128;
    int tid = threadIdx.x, lane = tid & 63, w = tid >> 6;
    int wr = w >> 1, wc = w & 1;
    int l15 = lane & 15, lg = lane >> 4;
    f32x4 acc[4][4];
    #pragma unroll
    for (int i=0;i<4;i++)
      #pragma unroll
      for (int j=0;j<4;j++)
        acc[i][j] = (f32x4){0.f,0.f,0.f,0.f};
    for (int kt = 0; kt < 8; ++kt) {
        #pragma unroll
        for (int i = 0; i < 8; ++i) {
            int f4 = i*256 + tid;
            int r  = f4 >> 4;
            int kp = (f4 & 15) * 4;
            f32x4 v = *(const f32x4*)(x + (size_t)(m0+r)*DD + kt*64 + kp);
            float2 st = *(const float2*)(stats + (size_t)(m0+r)*2);
            s16x4 h;
            h[0] = f2bf((v[0]-st.x)*st.y);
            h[1] = f2bf((v[1]-st.x)*st.y);
            h[2] = f2bf((v[2]-st.x)*st.y);
            h[3] = f2bf((v[3]-st.x)*st.y);
            *(s16x4*)(&As[r][kp]) = h;
        }
        #pragma unroll
        for (int i = 0; i < 4; ++i) {
            int f8 = i*256 + tid;
            int r  = f8 >> 3;
            int kp = (f8 & 7) * 8;
            *(s16x8*)(&Bs[r][kp]) = *(const s16x8*)(gateT + (size_t)(n0+r)*DD + kt*64 + kp);
        }
        __syncthreads();
        #pragma unroll
        for (int kk = 0; kk < 2; ++kk) {
            s16x8 af[4], bfr[4];
            #pragma unroll
            for (int mi=0;mi<4;mi++)
                af[mi] = *(const s16x8*)(&As[wr*64 + mi*16 + l15][kk*32 + lg*8]);
            #pragma unroll
            for (int ni=0;ni<4;ni++)
                bfr[ni] = *(const s16x8*)(&Bs[wc*64 + ni*16 + l15][kk*32 + lg*8]);
            #pragma unroll
            for (int mi=0;mi<4;mi++)
              #pragma unroll
              for (int ni=0;ni<4;ni++)
                acc[mi][ni] = __builtin_amdgcn_mfma_f32_16x16x32_bf16(af[mi], bfr[ni], acc[mi][ni], 0,0,0);
        }
        __syncthreads();
    }
    #pragma unroll
    for (int mi=0;mi<4;mi++)
      #pragma unroll
      for (int ni=0;ni<4;ni++) {
        int row0 = m0 + wr*64 + mi*16 + lg*4;
        int col  = n0 + wc*64 + ni*16 + l15;
        s16x4 h4;
        #pragma unroll
        for (int r=0;r<4;r++) h4[r] = f2bf(acc[mi][ni][r]);
        #pragma unroll
        for (int r=0;r<4;r++) qkv[(size_t)(row0+r)*DD + col] = h4[r];
        int b2 = row0 >> 10, t0 = row0 & 1023;
        *(s16x4*)(qkvT + (size_t)b2*DD*TT + (size_t)col*TT + t0) = h4;
      }
}

// ---- flash attention: 8 waves, 128q/block, swapped 32x32 MFMA, in-register softmax ----
// r5 structure (best measured) with conflict-free Sx chunk layout.
// wave w: q-subtile s=w&3 (32 rows), d-half dh=w>>2 (256 cols).
__global__ __launch_bounds__(512,2) void k_attn(const short* __restrict__ qkv,
                                                const short* __restrict__ qkvT,
                                                const float* __restrict__ xin,
                                                float* __restrict__ out) {
    __shared__ __align__(16) short Kt[2][16384];   // [buf][32 kv][512 d] rows 1KB, slot^=(kv&7)
    __shared__ __align__(16) short Vt[2][16384];   // [buf][512 d][32 kv] rows 64B, slot^=((d>>1)&3)
    __shared__ __align__(16) float Sx[8][1024];    // per-wave exchange: [4 chunks][64 lanes][4 f32]
    const float scale = 0.044194173824159216f;
    int bid = blockIdx.x;
    int batch = bid % NB;
    int qg = 7 - (bid / NB);                 // heavy qgroups dispatched first
    int tid = threadIdx.x, lane = tid & 63, w = tid >> 6;
    int s = w & 3, dh = w >> 2;
    int l31 = lane & 31, lh = lane >> 5;
    int qb = qg*128 + s*32;
    int qglob = qb + l31;
    const short* gq  = qkv  + (size_t)batch*TT*DD;
    const short* gvt = qkvT + (size_t)batch*DD*TT;

    // Q fragments (swapped QK^T B-operand): lane holds q=l31, its d-half
    s16x8 qf[16];
    {
        const short* qrow = gq + (size_t)qglob*DD + dh*256 + lh*8;
        #pragma unroll
        for (int kc=0;kc<16;kc++) qf[kc] = *(const s16x8*)(qrow + kc*16);
    }
    f32x16 o[8];
    #pragma unroll
    for (int m=0;m<8;m++)
        #pragma unroll
        for (int r=0;r<16;r++) o[m][r] = 0.f;
    float m_run = -1e30f, l_run = 0.f;
    int ntile = 4*(qg+1);

    auto stage = [&](int j, int c) {
        int kv0 = j*32;
        const char* ksrc = (const char*)(gq + (size_t)kv0*DD);
        char* kdst = (char*)&Kt[c][0];
        #pragma unroll
        for (int i=0;i<4;i++){
            int o16 = i*8192 + w*1024;          // wave-uniform LDS offset
            int ol  = o16 + (lane<<4);
            int go  = ol ^ (((ol>>10)&7)<<4);   // pre-swizzled global source (K)
            gll16(ksrc + go, kdst + o16);
        }
        const char* vsrc = (const char*)gvt;
        char* vdst = (char*)&Vt[c][0];
        #pragma unroll
        for (int i=0;i<4;i++){
            int o16 = i*8192 + w*1024;
            int ol  = o16 + (lane<<4);
            int d   = ol >> 6, c2 = ol & 63;
            int c2s = c2 ^ (((d>>1)&3)<<4);     // pre-swizzled global source (V)
            gll16(vsrc + (size_t)d*2048 + (size_t)kv0*2 + c2s, vdst + o16);
        }
    };

    stage(0, 0);
    __syncthreads();
    for (int kj = 0; kj < ntile; ++kj) {
        int cur = kj & 1;
        int kv0 = kj*32;
        if (kj + 1 < ntile) stage(kj+1, (kj+1)&1);
        const char* kbase = (const char*)&Kt[cur][0];
        const char* vbase = (const char*)&Vt[cur][0];
        // partial S^T over d-half: 16 x mfma(K, Q)
        f32x16 sT;
        #pragma unroll
        for (int r=0;r<16;r++) sT[r] = 0.f;
        #pragma unroll
        for (int kc=0;kc<16;kc++) {
            int boff = (dh*512 + kc*32 + lh*16) ^ ((l31 & 7) << 4);
            s16x8 kf = *(const s16x8*)(kbase + l31*1024 + boff);
            sT = __builtin_amdgcn_mfma_f32_32x32x16_bf16(kf, qf[kc], sT, 0,0,0);
        }
        // exchange partials with partner wave (w^4): [chunk][lane] contiguous layout
        {
            float* sw = &Sx[w][0];
            #pragma unroll
            for (int c=0;c<4;c++){
                f32x4 ch = (f32x4){sT[4*c],sT[4*c+1],sT[4*c+2],sT[4*c+3]};
                *(f32x4*)(sw + c*256 + lane*4) = ch;
            }
        }
        asm volatile("s_waitcnt lgkmcnt(0)\n\ts_barrier" ::: "memory");
        float p[16]; float mx = -1e30f;
        {
            const float* sr = &Sx[w^4][0];
            #pragma unroll
            for (int c=0;c<4;c++){
                f32x4 pc = *(const f32x4*)(sr + c*256 + lane*4);
                #pragma unroll
                for (int j=0;j<4;j++){
                    int r = 4*c + j;
                    float v = (sT[r] + pc[j]) * scale;
                    int kvr = kv0 + j + 8*c + 4*lh;
                    if (kvr > qglob) v = -1e30f;
                    p[r] = v;
                    mx = fmaxf(mx, v);
                }
            }
        }
        mx = fmaxf(mx, __shfl_xor(mx, 32));
        // defer-max rescale
        if (__any(mx > m_run)) {
            float mn = fmaxf(m_run, mx);
            float alpha = __expf(m_run - mn);
            m_run = mn;
            l_run *= alpha;
            #pragma unroll
            for (int m=0;m<8;m++)
                #pragma unroll
                for (int r=0;r<16;r++) o[m][r] *= alpha;
        }
        float ls = 0.f;
        #pragma unroll
        for (int r=0;r<16;r++){ p[r] = __expf(p[r] - m_run); ls += p[r]; }
        ls += __shfl_xor(ls, 32);
        l_run += ls;
        // pack P -> B-frags in-register (cvt_pk + permlane32_swap)
        s16x8 pb[2];
        #pragma unroll
        for (int km=0;km<2;km++){
            int b = 8*km;
            unsigned X0 = pk_bf16(p[b+0], p[b+1]);
            unsigned X1 = pk_bf16(p[b+2], p[b+3]);
            unsigned Y0 = pk_bf16(p[b+4], p[b+5]);
            unsigned Y1 = pk_bf16(p[b+6], p[b+7]);
            asm volatile("v_permlane32_swap_b32 %0, %1" : "+v"(X0), "+v"(Y0));
            asm volatile("v_permlane32_swap_b32 %0, %1" : "+v"(X1), "+v"(Y1));
            union { unsigned u[4]; s16x8 v; } pu;
            pu.u[0] = X0; pu.u[1] = X1; pu.u[2] = Y0; pu.u[3] = Y1;
            pb[km] = pu.v;
        }
        // PV swapped: O^T += V^T-frag x P-frag
        __builtin_amdgcn_s_setprio(1);
        #pragma unroll
        for (int m=0;m<8;m++){
            int row = dh*256 + m*32 + l31;
            #pragma unroll
            for (int km=0;km<2;km++){
                int boff = ((km*32 + lh*16) ^ (((row>>1)&3)<<4));
                s16x8 vf = *(const s16x8*)(vbase + (row<<6) + boff);
                o[m] = __builtin_amdgcn_mfma_f32_32x32x16_bf16(vf, pb[km], o[m], 0,0,0);
            }
        }
        __builtin_amdgcn_s_setprio(0);
        __syncthreads();   // drains vmcnt: next-tile stage landed; all waves done with cur
    }
    // epilogue: O^T -> transpose via LDS (reuse Kt) -> coalesced global store
    float inv = 1.0f / l_run;
    #pragma unroll
    for (int m=0;m<8;m++)
        #pragma unroll
        for (int r=0;r<16;r++) o[m][r] *= inv;
    float* T = (float*)&Kt[0][0] + w*1152;   // 32 x 36 f32 per wave
    #pragma unroll
    for (int m=0;m<8;m++){
        #pragma unroll
        for (int r=0;r<16;r++){
            int dloc = (r&3) + 8*(r>>2) + 4*lh;
            T[l31*36 + dloc] = o[m][r];
        }
        __builtin_amdgcn_s_waitcnt(0);  // lgkmcnt(0): writes visible to own wave reads
        #pragma unroll
        for (int p2=0;p2<4;p2++){
            int qr = p2*8 + (lane>>3);
            f32x4 t = *(const f32x4*)(T + qr*36 + (lane&7)*4);
            size_t gofs = ((size_t)batch*TT + qb + qr)*DD + dh*256 + m*32 + (lane&7)*4;
            f32x4 xi = *(const f32x4*)(xin + gofs);
            *(f32x4*)(out + gofs) = t + xi;
        }
        __builtin_amdgcn_s_waitcnt(0);  // reads done before next m-tile overwrites T
    }
}

// ---------------- cross-cell mix + tanh + pulse (in place on d_out) ----------------
__device__ __forceinline__ float tanh_fast(float x) {
    float e = __expf(2.0f*x);
    return 1.0f - __fdividef(2.0f, e + 1.0f);
}

__global__ __launch_bounds__(256) void k_post(float* __restrict__ xo,
                                              const float* __restrict__ inhibit,
                                              const float* __restrict__ phases,
                                              const float* __restrict__ ambition) {
    int idx = blockIdx.x*256 + threadIdx.x;
    int b = idx >> 17;
    int rem = idx & 131071;
    size_t base = (size_t)b*6*TT*DD + (size_t)(rem >> 7)*DD + (size_t)(rem & 127)*4;
    f32x4 v[6];
    #pragma unroll
    for (int c=0;c<6;c++) v[c] = *(const f32x4*)(xo + base + (size_t)c*TT*DD);
    float inh[36];
    #pragma unroll
    for (int i=0;i<36;i++) inh[i] = inhibit[i];
    #pragma unroll
    for (int k=0;k<6;k++){
        float c0=0.f, c1=0.f, c2=0.f, c3=0.f;
        #pragma unroll
        for (int c=0;c<6;c++){
            float wv = inh[c*6+k];
            c0 += v[c][0]*wv; c1 += v[c][1]*wv;
            c2 += v[c][2]*wv; c3 += v[c][3]*wv;
        }
        float a = ambition[k], ph = phases[k];
        float x0 = v[k][0] + tanh_fast(c0);
        float x1 = v[k][1] + tanh_fast(c1);
        float x2 = v[k][2] + tanh_fast(c2);
        float x3 = v[k][3] + tanh_fast(c3);
        f32x4 ov;
        ov[0] = x0 + __sinf(x0*a + ph)*0.02f;
        ov[1] = x1 + __sinf(x1*a + ph)*0.02f;
        ov[2] = x2 + __sinf(x2*a + ph)*0.02f;
        ov[3] = x3 + __sinf(x3*a + ph)*0.02f;
        *(f32x4*)(xo + base + (size_t)k*TT*DD) = ov;
    }
}

extern "C" void kernel_launch(void* const* d_in, const int* in_sizes, int n_in,
                              void* d_out, int out_size, void* d_ws, size_t ws_size,
                              hipStream_t stream) {
    (void)in_sizes; (void)n_in; (void)out_size; (void)ws_size;
    const float* x        = (const float*)d_in[0];
    const float* gate     = (const float*)d_in[2];
    const float* inhibit  = (const float*)d_in[3];
    const float* phases   = (const float*)d_in[4];
    const float* ambition = (const float*)d_in[5];
    float* out = (float*)d_out;
    char* ws = (char*)d_ws;
    short* qkv   = (short*)(ws);                    // 50331648 B
    short* qkvT  = (short*)(ws + 50331648);         // 50331648 B
    float* stats = (float*)(ws + 100663296);        // 393216 B
    short* gateT = (short*)(ws + 101056512);        // 524288 B

    k_ln_stats <<<dim3(12288), dim3(256), 0, stream>>>(x, stats);
    k_gate_t   <<<dim3(64),    dim3(256), 0, stream>>>(gate, gateT);
    k_qkv      <<<dim3(1536),  dim3(256), 0, stream>>>(x, stats, gateT, qkv, qkvT);
    k_attn     <<<dim3(384),   dim3(512), 0, stream>>>(qkv, qkvT, x, out);
    k_post     <<<dim3(4096),  dim3(256), 0, stream>>>(out, inhibit, phases, ambition);
}

// Round 10
// 267.645 us; speedup vs baseline: 1.5252x; 1.0490x over previous
//
#include <hip/hip_runtime.h>
#include <math.h>

typedef __attribute__((ext_vector_type(4))) float f32x4;
typedef __attribute__((ext_vector_type(16))) float f32x16;
typedef __attribute__((ext_vector_type(8))) short s16x8;
typedef __attribute__((ext_vector_type(4))) short s16x4;

#define DD 512
#define TT 1024
#define NB 48

__device__ __forceinline__ short f2bf(float f) {
    union { float f; unsigned u; } v; v.f = f;
    unsigned r = v.u + 0x7fffu + ((v.u >> 16) & 1u);
    return (short)(r >> 16);
}

__device__ __forceinline__ void gll16(const void* g, void* l) {
    __builtin_amdgcn_global_load_lds(
        (const __attribute__((address_space(1))) unsigned int*)g,
        (__attribute__((address_space(3))) unsigned int*)l, 16, 0, 0);
}

__device__ __forceinline__ unsigned pk_bf16(float lo, float hi) {
    unsigned r;
    asm("v_cvt_pk_bf16_f32 %0, %1, %2" : "=v"(r) : "v"(lo), "v"(hi));
    return r;
}

// ---------------- LayerNorm stats: one wave per row ----------------
__global__ __launch_bounds__(256) void k_ln_stats(const float* __restrict__ x,
                                                  float* __restrict__ stats) {
    int row = blockIdx.x * 4 + (threadIdx.x >> 6);
    int lane = threadIdx.x & 63;
    const float* p = x + (size_t)row * DD + lane * 8;
    f32x4 a = *(const f32x4*)p;
    f32x4 b = *(const f32x4*)(p + 4);
    float s  = a[0]+a[1]+a[2]+a[3]+b[0]+b[1]+b[2]+b[3];
    float ss = a[0]*a[0]+a[1]*a[1]+a[2]*a[2]+a[3]*a[3]
             + b[0]*b[0]+b[1]*b[1]+b[2]*b[2]+b[3]*b[3];
    #pragma unroll
    for (int off = 32; off >= 1; off >>= 1) {
        s  += __shfl_xor(s, off);
        ss += __shfl_xor(ss, off);
    }
    if (lane == 0) {
        float mu  = s * (1.0f/DD);
        float var = ss * (1.0f/DD) - mu*mu;
        float2 st; st.x = mu; st.y = rsqrtf(var + 1e-5f);
        *(float2*)(stats + (size_t)row*2) = st;
    }
}

// ---------------- gate -> gateT (bf16) ----------------
__global__ __launch_bounds__(256) void k_gate_t(const float* __restrict__ gate,
                                                short* __restrict__ gateT) {
    __shared__ float tile[64][65];
    int k0 = (blockIdx.x >> 3) * 64;
    int n0 = (blockIdx.x & 7) * 64;
    int tid = threadIdx.x;
    #pragma unroll
    for (int i = 0; i < 16; ++i) {
        int f = i*256 + tid;
        int r = f >> 6, c = f & 63;
        tile[r][c] = gate[(size_t)(k0+r)*DD + n0 + c];
    }
    __syncthreads();
    #pragma unroll
    for (int i = 0; i < 16; ++i) {
        int f = i*256 + tid;
        int r = f >> 6, c = f & 63;
        gateT[(size_t)(n0+r)*DD + k0 + c] = f2bf(tile[c][r]);
    }
}

// ------- qkv = LN(x) @ gate; writes qkv row-major + qkvT in TILED layout -------
// qkvT2[batch][t>>5][d][t&31]: each KV-tile's V^T is a contiguous 32KB block.
__global__ __launch_bounds__(256,2) void k_qkv(const float* __restrict__ x,
                                               const float* __restrict__ stats,
                                               const short* __restrict__ gateT,
                                               short* __restrict__ qkv,
                                               short* __restrict__ qkvT) {
    __shared__ __align__(16) short As[128][72];
    __shared__ __align__(16) short Bs[128][72];
    int m0 = (blockIdx.x >> 2) * 128;
    int n0 = (blockIdx.x & 3) * 128;
    int tid = threadIdx.x, lane = tid & 63, w = tid >> 6;
    int wr = w >> 1, wc = w & 1;
    int l15 = lane & 15, lg = lane >> 4;
    f32x4 acc[4][4];
    #pragma unroll
    for (int i=0;i<4;i++)
      #pragma unroll
      for (int j=0;j<4;j++)
        acc[i][j] = (f32x4){0.f,0.f,0.f,0.f};
    for (int kt = 0; kt < 8; ++kt) {
        #pragma unroll
        for (int i = 0; i < 8; ++i) {
            int f4 = i*256 + tid;
            int r  = f4 >> 4;
            int kp = (f4 & 15) * 4;
            f32x4 v = *(const f32x4*)(x + (size_t)(m0+r)*DD + kt*64 + kp);
            float2 st = *(const float2*)(stats + (size_t)(m0+r)*2);
            s16x4 h;
            h[0] = f2bf((v[0]-st.x)*st.y);
            h[1] = f2bf((v[1]-st.x)*st.y);
            h[2] = f2bf((v[2]-st.x)*st.y);
            h[3] = f2bf((v[3]-st.x)*st.y);
            *(s16x4*)(&As[r][kp]) = h;
        }
        #pragma unroll
        for (int i = 0; i < 4; ++i) {
            int f8 = i*256 + tid;
            int r  = f8 >> 3;
            int kp = (f8 & 7) * 8;
            *(s16x8*)(&Bs[r][kp]) = *(const s16x8*)(gateT + (size_t)(n0+r)*DD + kt*64 + kp);
        }
        __syncthreads();
        #pragma unroll
        for (int kk = 0; kk < 2; ++kk) {
            s16x8 af[4], bfr[4];
            #pragma unroll
            for (int mi=0;mi<4;mi++)
                af[mi] = *(const s16x8*)(&As[wr*64 + mi*16 + l15][kk*32 + lg*8]);
            #pragma unroll
            for (int ni=0;ni<4;ni++)
                bfr[ni] = *(const s16x8*)(&Bs[wc*64 + ni*16 + l15][kk*32 + lg*8]);
            #pragma unroll
            for (int mi=0;mi<4;mi++)
              #pragma unroll
              for (int ni=0;ni<4;ni++)
                acc[mi][ni] = __builtin_amdgcn_mfma_f32_16x16x32_bf16(af[mi], bfr[ni], acc[mi][ni], 0,0,0);
        }
        __syncthreads();
    }
    #pragma unroll
    for (int mi=0;mi<4;mi++)
      #pragma unroll
      for (int ni=0;ni<4;ni++) {
        int row0 = m0 + wr*64 + mi*16 + lg*4;
        int col  = n0 + wc*64 + ni*16 + l15;
        s16x4 h4;
        #pragma unroll
        for (int r=0;r<4;r++) h4[r] = f2bf(acc[mi][ni][r]);
        #pragma unroll
        for (int r=0;r<4;r++) qkv[(size_t)(row0+r)*DD + col] = h4[r];
        int b2 = row0 >> 10, t0 = row0 & 1023;
        // tiled qkvT: [b][t>>5][d][t&31]
        *(s16x4*)(qkvT + (size_t)b2*DD*TT + (size_t)(t0>>5)*16384
                       + (size_t)col*32 + (t0&31)) = h4;
      }
}

// ---- flash attention: 8 waves, 128q/block, swapped 32x32 MFMA, in-register softmax ----
// r9 structure + tile-contiguous V staging + 5-bit K swizzle + THR=8 defer-max.
__global__ __launch_bounds__(512,2) void k_attn(const short* __restrict__ qkv,
                                                const short* __restrict__ qkvT,
                                                const float* __restrict__ xin,
                                                float* __restrict__ out) {
    __shared__ __align__(16) short Kt[2][16384];   // [buf][32 kv][512 d] rows 1KB, slot^=(kv&31)
    __shared__ __align__(16) short Vt[2][16384];   // [buf][512 d][32 kv] rows 64B, slot^=((d>>1)&3)
    __shared__ __align__(16) float Sx[8][1024];    // per-wave exchange: [4 chunks][64 lanes][4 f32]
    const float scale = 0.044194173824159216f;
    int bid = blockIdx.x;
    int batch = bid % NB;
    int qg = 7 - (bid / NB);                 // heavy qgroups dispatched first
    int tid = threadIdx.x, lane = tid & 63, w = tid >> 6;
    int s = w & 3, dh = w >> 2;
    int l31 = lane & 31, lh = lane >> 5;
    int qb = qg*128 + s*32;
    int qglob = qb + l31;
    const short* gq  = qkv  + (size_t)batch*TT*DD;
    const short* gvt = qkvT + (size_t)batch*DD*TT;   // tiled layout

    // Q fragments (swapped QK^T B-operand): lane holds q=l31, its d-half
    s16x8 qf[16];
    {
        const short* qrow = gq + (size_t)qglob*DD + dh*256 + lh*8;
        #pragma unroll
        for (int kc=0;kc<16;kc++) qf[kc] = *(const s16x8*)(qrow + kc*16);
    }
    f32x16 o[8];
    #pragma unroll
    for (int m=0;m<8;m++)
        #pragma unroll
        for (int r=0;r<16;r++) o[m][r] = 0.f;
    float m_run = -1e30f, l_run = 0.f;
    int ntile = 4*(qg+1);

    auto stage = [&](int j, int c) {
        const char* ksrc = (const char*)(gq + (size_t)(j*32)*DD);
        char* kdst = (char*)&Kt[c][0];
        #pragma unroll
        for (int i=0;i<4;i++){
            int o16 = i*8192 + w*1024;          // wave-uniform LDS offset
            int ol  = o16 + (lane<<4);
            int go  = ol ^ (((ol>>10)&31)<<4);  // 5-bit pre-swizzle (K)
            gll16(ksrc + go, kdst + o16);
        }
        const char* vsrc = (const char*)(gvt + (size_t)j*16384);  // contiguous tile
        char* vdst = (char*)&Vt[c][0];
        #pragma unroll
        for (int i=0;i<4;i++){
            int o16 = i*8192 + w*1024;
            int ol  = o16 + (lane<<4);
            int go  = ol ^ (((ol>>7)&3)<<4);    // pre-swizzle (V), line-perfect source
            gll16(vsrc + go, vdst + o16);
        }
    };

    stage(0, 0);
    __syncthreads();
    for (int kj = 0; kj < ntile; ++kj) {
        int cur = kj & 1;
        int kv0 = kj*32;
        if (kj + 1 < ntile) stage(kj+1, (kj+1)&1);
        const char* kbase = (const char*)&Kt[cur][0];
        const char* vbase = (const char*)&Vt[cur][0];
        // partial S^T over d-half: 16 x mfma(K, Q)
        f32x16 sT;
        #pragma unroll
        for (int r=0;r<16;r++) sT[r] = 0.f;
        #pragma unroll
        for (int kc=0;kc<16;kc++) {
            int boff = (dh*512 + kc*32 + lh*16) ^ (l31 << 4);
            s16x8 kf = *(const s16x8*)(kbase + l31*1024 + boff);
            sT = __builtin_amdgcn_mfma_f32_32x32x16_bf16(kf, qf[kc], sT, 0,0,0);
        }
        // exchange partials with partner wave (w^4): [chunk][lane] contiguous layout
        {
            float* sw = &Sx[w][0];
            #pragma unroll
            for (int c=0;c<4;c++){
                f32x4 ch = (f32x4){sT[4*c],sT[4*c+1],sT[4*c+2],sT[4*c+3]};
                *(f32x4*)(sw + c*256 + lane*4) = ch;
            }
        }
        asm volatile("s_waitcnt lgkmcnt(0)\n\ts_barrier" ::: "memory");
        float p[16]; float mx = -1e30f;
        {
            const float* sr = &Sx[w^4][0];
            #pragma unroll
            for (int c=0;c<4;c++){
                f32x4 pc = *(const f32x4*)(sr + c*256 + lane*4);
                #pragma unroll
                for (int j=0;j<4;j++){
                    int r = 4*c + j;
                    float v = (sT[r] + pc[j]) * scale;
                    int kvr = kv0 + j + 8*c + 4*lh;
                    if (kvr > qglob) v = -1e30f;
                    p[r] = v;
                    mx = fmaxf(mx, v);
                }
            }
        }
        mx = fmaxf(mx, __shfl_xor(mx, 32));
        // defer-max (T13): rescale only when max grows by more than THR=8
        if (__any(mx > m_run + 8.0f)) {
            float mn = fmaxf(m_run, mx);
            float alpha = __expf(m_run - mn);
            m_run = mn;
            l_run *= alpha;
            #pragma unroll
            for (int m=0;m<8;m++)
                #pragma unroll
                for (int r=0;r<16;r++) o[m][r] *= alpha;
        }
        float ls = 0.f;
        #pragma unroll
        for (int r=0;r<16;r++){ p[r] = __expf(p[r] - m_run); ls += p[r]; }
        ls += __shfl_xor(ls, 32);
        l_run += ls;
        // pack P -> B-frags in-register (cvt_pk + permlane32_swap)
        s16x8 pb[2];
        #pragma unroll
        for (int km=0;km<2;km++){
            int b = 8*km;
            unsigned X0 = pk_bf16(p[b+0], p[b+1]);
            unsigned X1 = pk_bf16(p[b+2], p[b+3]);
            unsigned Y0 = pk_bf16(p[b+4], p[b+5]);
            unsigned Y1 = pk_bf16(p[b+6], p[b+7]);
            asm volatile("v_permlane32_swap_b32 %0, %1" : "+v"(X0), "+v"(Y0));
            asm volatile("v_permlane32_swap_b32 %0, %1" : "+v"(X1), "+v"(Y1));
            union { unsigned u[4]; s16x8 v; } pu;
            pu.u[0] = X0; pu.u[1] = X1; pu.u[2] = Y0; pu.u[3] = Y1;
            pb[km] = pu.v;
        }
        // PV swapped: O^T += V^T-frag x P-frag
        __builtin_amdgcn_s_setprio(1);
        #pragma unroll
        for (int m=0;m<8;m++){
            int row = dh*256 + m*32 + l31;
            #pragma unroll
            for (int km=0;km<2;km++){
                int boff = ((km*32 + lh*16) ^ (((row>>1)&3)<<4));
                s16x8 vf = *(const s16x8*)(vbase + (row<<6) + boff);
                o[m] = __builtin_amdgcn_mfma_f32_32x32x16_bf16(vf, pb[km], o[m], 0,0,0);
            }
        }
        __builtin_amdgcn_s_setprio(0);
        __syncthreads();   // drains vmcnt: next-tile stage landed; all waves done with cur
    }
    // epilogue: O^T -> transpose via LDS (reuse Kt) -> coalesced global store
    float inv = 1.0f / l_run;
    #pragma unroll
    for (int m=0;m<8;m++)
        #pragma unroll
        for (int r=0;r<16;r++) o[m][r] *= inv;
    float* T = (float*)&Kt[0][0] + w*1152;   // 32 x 36 f32 per wave
    #pragma unroll
    for (int m=0;m<8;m++){
        #pragma unroll
        for (int r=0;r<16;r++){
            int dloc = (r&3) + 8*(r>>2) + 4*lh;
            T[l31*36 + dloc] = o[m][r];
        }
        __builtin_amdgcn_s_waitcnt(0);  // lgkmcnt(0): writes visible to own wave reads
        #pragma unroll
        for (int p2=0;p2<4;p2++){
            int qr = p2*8 + (lane>>3);
            f32x4 t = *(const f32x4*)(T + qr*36 + (lane&7)*4);
            size_t gofs = ((size_t)batch*TT + qb + qr)*DD + dh*256 + m*32 + (lane&7)*4;
            f32x4 xi = *(const f32x4*)(xin + gofs);
            *(f32x4*)(out + gofs) = t + xi;
        }
        __builtin_amdgcn_s_waitcnt(0);  // reads done before next m-tile overwrites T
    }
}

// ---------------- cross-cell mix + tanh + pulse (in place on d_out) ----------------
__device__ __forceinline__ float tanh_fast(float x) {
    float e = __expf(2.0f*x);
    return 1.0f - __fdividef(2.0f, e + 1.0f);
}

__global__ __launch_bounds__(256) void k_post(float* __restrict__ xo,
                                              const float* __restrict__ inhibit,
                                              const float* __restrict__ phases,
                                              const float* __restrict__ ambition) {
    int idx = blockIdx.x*256 + threadIdx.x;
    int b = idx >> 17;
    int rem = idx & 131071;
    size_t base = (size_t)b*6*TT*DD + (size_t)(rem >> 7)*DD + (size_t)(rem & 127)*4;
    f32x4 v[6];
    #pragma unroll
    for (int c=0;c<6;c++) v[c] = *(const f32x4*)(xo + base + (size_t)c*TT*DD);
    float inh[36];
    #pragma unroll
    for (int i=0;i<36;i++) inh[i] = inhibit[i];
    #pragma unroll
    for (int k=0;k<6;k++){
        float c0=0.f, c1=0.f, c2=0.f, c3=0.f;
        #pragma unroll
        for (int c=0;c<6;c++){
            float wv = inh[c*6+k];
            c0 += v[c][0]*wv; c1 += v[c][1]*wv;
            c2 += v[c][2]*wv; c3 += v[c][3]*wv;
        }
        float a = ambition[k], ph = phases[k];
        float x0 = v[k][0] + tanh_fast(c0);
        float x1 = v[k][1] + tanh_fast(c1);
        float x2 = v[k][2] + tanh_fast(c2);
        float x3 = v[k][3] + tanh_fast(c3);
        f32x4 ov;
        ov[0] = x0 + __sinf(x0*a + ph)*0.02f;
        ov[1] = x1 + __sinf(x1*a + ph)*0.02f;
        ov[2] = x2 + __sinf(x2*a + ph)*0.02f;
        ov[3] = x3 + __sinf(x3*a + ph)*0.02f;
        *(f32x4*)(xo + base + (size_t)k*TT*DD) = ov;
    }
}

extern "C" void kernel_launch(void* const* d_in, const int* in_sizes, int n_in,
                              void* d_out, int out_size, void* d_ws, size_t ws_size,
                              hipStream_t stream) {
    (void)in_sizes; (void)n_in; (void)out_size; (void)ws_size;
    const float* x        = (const float*)d_in[0];
    const float* gate     = (const float*)d_in[2];
    const float* inhibit  = (const float*)d_in[3];
    const float* phases   = (const float*)d_in[4];
    const float* ambition = (const float*)d_in[5];
    float* out = (float*)d_out;
    char* ws = (char*)d_ws;
    short* qkv   = (short*)(ws);                    // 50331648 B
    short* qkvT  = (short*)(ws + 50331648);         // 50331648 B (tiled layout)
    float* stats = (float*)(ws + 100663296);        // 393216 B
    short* gateT = (short*)(ws + 101056512);        // 524288 B

    k_ln_stats <<<dim3(12288), dim3(256), 0, stream>>>(x, stats);
    k_gate_t   <<<dim3(64),    dim3(256), 0, stream>>>(gate, gateT);
    k_qkv      <<<dim3(1536),  dim3(256), 0, stream>>>(x, stats, gateT, qkv, qkvT);
    k_attn     <<<dim3(384),   dim3(512), 0, stream>>>(qkv, qkvT, x, out);
    k_post     <<<dim3(4096),  dim3(256), 0, stream>>>(out, inhibit, phases, ambition);
}